// Round 1
// baseline (541.096 us; speedup 1.0000x reference)
//
#include <hip/hip_runtime.h>
#include <math.h>

#define BS 2
#define NQ 21760
#define V_LEN 21760
#define EMBED 256
#define NH 8
#define NL 4
#define NP 4
#define HD 32

// ---------------- GEMM: C[M,N] = A[M,K] @ W[K,N] + bias[N] (all row-major fp32)
#define BM 64
#define BN 64
#define BK 32

__global__ __launch_bounds__(256) void gemm_bias(
    const float* __restrict__ A, const float* __restrict__ W,
    const float* __restrict__ bias, float* __restrict__ C,
    int M, int N, int K)
{
    __shared__ __align__(16) float As[BK][BM + 4];   // transposed A tile: As[k][m]
    __shared__ __align__(16) float Ws[BK][BN + 4];   // Ws[k][n]
    const int bm = blockIdx.x * BM;
    const int bn = blockIdx.y * BN;
    const int tid = threadIdx.x;
    const int tx = tid & 15, ty = tid >> 4;

    float acc[4][4] = {};

    for (int k0 = 0; k0 < K; k0 += BK) {
        // Load A tile (64 rows x 32 k) as float4, store transposed
        #pragma unroll
        for (int i = 0; i < 2; i++) {
            int idx = tid + i * 256;        // 0..511
            int row = idx >> 3;             // 8 float4 per row
            int kc  = (idx & 7) << 2;
            float4 av = *(const float4*)&A[(size_t)(bm + row) * K + k0 + kc];
            As[kc + 0][row] = av.x;
            As[kc + 1][row] = av.y;
            As[kc + 2][row] = av.z;
            As[kc + 3][row] = av.w;
        }
        // Load W tile (32 k x 64 n) as float4, direct layout
        #pragma unroll
        for (int i = 0; i < 2; i++) {
            int idx = tid + i * 256;
            int kk = idx >> 4;              // 16 float4 per k-row
            int nc = (idx & 15) << 2;
            *(float4*)&Ws[kk][nc] = *(const float4*)&W[(size_t)(k0 + kk) * N + bn + nc];
        }
        __syncthreads();
        #pragma unroll
        for (int k = 0; k < BK; k++) {
            float4 a = *(const float4*)&As[k][ty << 2];
            float4 b = *(const float4*)&Ws[k][tx << 2];
            float av4[4] = {a.x, a.y, a.z, a.w};
            float bv4[4] = {b.x, b.y, b.z, b.w};
            #pragma unroll
            for (int r = 0; r < 4; r++)
                #pragma unroll
                for (int c = 0; c < 4; c++)
                    acc[r][c] += av4[r] * bv4[c];
        }
        __syncthreads();
    }

    const int row0 = bm + (ty << 2);
    const int col0 = bn + (tx << 2);
    float4 bv = *(const float4*)&bias[col0];
    #pragma unroll
    for (int r = 0; r < 4; r++) {
        float4 o;
        o.x = acc[r][0] + bv.x;
        o.y = acc[r][1] + bv.y;
        o.z = acc[r][2] + bv.z;
        o.w = acc[r][3] + bv.w;
        *(float4*)&C[(size_t)(row0 + r) * N + col0] = o;
    }
}

// ---------------- Deformable sampling: one wave (64 threads) per query.
// Reads off (from offsam), attn logits (awl), reference points; does softmax,
// computes bilinear corner indices/weights in LDS, gathers from vproj,
// writes sampled output IN PLACE over offsam (same query slice only).
__global__ __launch_bounds__(64) void deform_sample(
    const float* __restrict__ vproj,   // [BS, V, NH, HD] = [BS*V*256]
    float* offsam,                     // [BS*NQ*256]: in = off, out = sampled
    const float* __restrict__ awl,     // [BS*NQ*128] attn logits
    const float* __restrict__ refp)    // [BS*NQ*NL*2]
{
    const int q = blockIdx.x;
    const int b = blockIdx.y;
    const int bq = b * NQ + q;
    const int t = threadIdx.x;

    __shared__ float s_off[256];
    __shared__ float s_aw[128];
    __shared__ __align__(16) float s_w[128][4];
    __shared__ __align__(16) int   s_idx[128][4];

    const float* offp = offsam + (size_t)bq * 256;
    #pragma unroll
    for (int i = 0; i < 4; i++) s_off[t + i * 64] = offp[t + i * 64];
    #pragma unroll
    for (int i = 0; i < 2; i++) s_aw[t + i * 64] = awl[(size_t)bq * 128 + t + i * 64];
    __syncthreads();

    // Softmax per (head): 8 groups of 16
    if (t < 8) {
        float m = -1e30f;
        #pragma unroll
        for (int i = 0; i < 16; i++) m = fmaxf(m, s_aw[t * 16 + i]);
        float ssum = 0.f;
        #pragma unroll
        for (int i = 0; i < 16; i++) {
            float e = __expf(s_aw[t * 16 + i] - m);
            s_aw[t * 16 + i] = e;
            ssum += e;
        }
        float r = 1.0f / ssum;
        #pragma unroll
        for (int i = 0; i < 16; i++) s_aw[t * 16 + i] *= r;
    }
    __syncthreads();

    // Precompute 128 samples: corner row indices (clamped, always valid) and
    // bilinear weights fused with attention weight (zeroed when OOB).
    #pragma unroll
    for (int sI = 0; sI < 2; sI++) {
        int s = t + sI * 64;
        int h = s >> 4, lp = s & 15, l = lp >> 2, p = lp & 3;
        int Wl = 128 >> l, Hl = 128 >> l;
        int st = (l == 0) ? 0 : (l == 1) ? 16384 : (l == 2) ? 20480 : 21504;
        float rx = refp[((size_t)bq * 4 + l) * 2 + 0];
        float ry = refp[((size_t)bq * 4 + l) * 2 + 1];
        float ox = s_off[((h * NL + l) * NP + p) * 2 + 0];
        float oy = s_off[((h * NL + l) * NP + p) * 2 + 1];
        float fW = (float)Wl, fH = (float)Hl;
        float x = (rx + ox / fW) * fW - 0.5f;
        float y = (ry + oy / fH) * fH - 0.5f;
        float xf = floorf(x), yf = floorf(y);
        int x0 = (int)xf, y0 = (int)yf;
        float wx1 = x - xf, wx0 = 1.f - wx1;
        float wy1 = y - yf, wy0 = 1.f - wy1;
        float aw = s_aw[h * 16 + lp];
        bool vx0 = (x0 >= 0) && (x0 < Wl);
        bool vx1 = (x0 + 1 >= 0) && (x0 + 1 < Wl);
        bool vy0 = (y0 >= 0) && (y0 < Hl);
        bool vy1 = (y0 + 1 >= 0) && (y0 + 1 < Hl);
        int cx0 = min(max(x0, 0), Wl - 1), cx1 = min(max(x0 + 1, 0), Wl - 1);
        int cy0 = min(max(y0, 0), Hl - 1), cy1 = min(max(y0 + 1, 0), Hl - 1);
        s_idx[s][0] = st + cy0 * Wl + cx0;  s_w[s][0] = (vy0 && vx0) ? wy0 * wx0 * aw : 0.f;
        s_idx[s][1] = st + cy0 * Wl + cx1;  s_w[s][1] = (vy0 && vx1) ? wy0 * wx1 * aw : 0.f;
        s_idx[s][2] = st + cy1 * Wl + cx0;  s_w[s][2] = (vy1 && vx0) ? wy1 * wx0 * aw : 0.f;
        s_idx[s][3] = st + cy1 * Wl + cx1;  s_w[s][3] = (vy1 && vx1) ? wy1 * wx1 * aw : 0.f;
    }
    __syncthreads();

    // Gather & accumulate. Thread owns channels c = i*64 + t.
    const float* vb = vproj + (size_t)b * V_LEN * EMBED;
    float acc[4];
    #pragma unroll
    for (int i = 0; i < 4; i++) {
        const int c = i * 64 + t;
        const int h = c >> 5;
        float a = 0.f;
        #pragma unroll 4
        for (int lp = 0; lp < 16; lp++) {
            const int s = h * 16 + lp;
            const float4 w4 = *(const float4*)&s_w[s][0];
            const int4  i4 = *(const int4*)&s_idx[s][0];
            a += w4.x * vb[(size_t)i4.x * EMBED + c];
            a += w4.y * vb[(size_t)i4.y * EMBED + c];
            a += w4.z * vb[(size_t)i4.z * EMBED + c];
            a += w4.w * vb[(size_t)i4.w * EMBED + c];
        }
        acc[i] = a;
    }

    // Write sampled output in place (this block's query slice only; all LDS
    // consumers of s_off finished at the barrier above).
    float* op = offsam + (size_t)bq * 256;
    #pragma unroll
    for (int i = 0; i < 4; i++) op[i * 64 + t] = acc[i];
}

extern "C" void kernel_launch(void* const* d_in, const int* in_sizes, int n_in,
                              void* d_out, int out_size, void* d_ws, size_t ws_size,
                              hipStream_t stream)
{
    const float* query  = (const float*)d_in[0];
    const float* refp   = (const float*)d_in[1];
    const float* value  = (const float*)d_in[2];
    const float* W_off  = (const float*)d_in[3];
    const float* b_off  = (const float*)d_in[4];
    const float* W_attn = (const float*)d_in[5];
    const float* b_attn = (const float*)d_in[6];
    const float* W_v    = (const float*)d_in[7];
    const float* b_v    = (const float*)d_in[8];
    const float* W_out  = (const float*)d_in[9];
    const float* b_out  = (const float*)d_in[10];
    float* out = (float*)d_out;

    const int M = BS * NQ;  // 43520
    float* ws     = (float*)d_ws;
    float* vproj  = ws;                        // M*256 floats
    float* offsam = vproj + (size_t)M * 256;   // M*256 floats (off, then sampled)
    float* awl    = offsam + (size_t)M * 256;  // M*128 floats

    dim3 blk(256);
    // v = value @ W_v + b_v
    gemm_bias<<<dim3(M / BM, EMBED / BN), blk, 0, stream>>>(value, W_v, b_v, vproj, M, 256, 256);
    // off = query @ W_off + b_off
    gemm_bias<<<dim3(M / BM, EMBED / BN), blk, 0, stream>>>(query, W_off, b_off, offsam, M, 256, 256);
    // attn logits = query @ W_attn + b_attn
    gemm_bias<<<dim3(M / BM, 128 / BN), blk, 0, stream>>>(query, W_attn, b_attn, awl, M, 128, 256);
    // softmax + deformable sampling (writes sampled over offsam)
    deform_sample<<<dim3(NQ, BS), dim3(64), 0, stream>>>(vproj, offsam, awl, refp);
    // out = sampled @ W_out + b_out
    gemm_bias<<<dim3(M / BM, EMBED / BN), blk, 0, stream>>>(offsam, W_out, b_out, out, M, 256, 256);
}

// Round 2
// 300.629 us; speedup vs baseline: 1.7999x; 1.7999x over previous
//
#include <hip/hip_runtime.h>
#include <math.h>

#define BS 2
#define NQ 21760
#define V_LEN 21760
#define EMBED 256
#define NH 8
#define NL 4
#define NP 4
#define HD 32

typedef __bf16 bf16;
typedef __bf16 bf16x8 __attribute__((ext_vector_type(8)));
typedef __bf16 bf16x4 __attribute__((ext_vector_type(4)));
typedef float f32x4 __attribute__((ext_vector_type(4)));

// ---------------- weight transpose+cast: WT[n][k] = bf16(W[k][n]), K=256 fixed
__global__ __launch_bounds__(256) void cast_wt(const float* __restrict__ W,
                                               bf16* __restrict__ WT, int N)
{
    int id = blockIdx.x * 256 + threadIdx.x;   // total 256*N
    int n = id >> 8, k = id & 255;
    WT[id] = (bf16)W[k * N + n];
}

__global__ __launch_bounds__(384) void concat_bias(const float* __restrict__ b_off,
                                                   const float* __restrict__ b_attn,
                                                   float* __restrict__ bc)
{
    int id = threadIdx.x;  // 384
    bc[id] = (id < 256) ? b_off[id] : b_attn[id - 256];
}

// ---------------- bf16 MFMA GEMM: C[M,N] = A[M,K] @ WT^T + bias
// A: fp32 (cast in staging) or bf16. WT: [N][K] bf16. Tile 128x128, BK=32.
template<bool A_BF16, bool OUT_BF16>
__global__ __launch_bounds__(256) void gemm_mfma(
    const void* __restrict__ Av, const bf16* __restrict__ WT,
    const float* __restrict__ bias, void* __restrict__ Cv,
    int N, int K, int ntn)
{
    const int bnt = blockIdx.x % ntn;     // col-fastest: A panel reused by adjacent blocks
    const int bmt = blockIdx.x / ntn;
    const int bm = bmt * 128, bn = bnt * 128;

    __shared__ __align__(16) bf16 As[128][40];  // row stride 80 B (16B-aligned, 2-way banks)
    __shared__ __align__(16) bf16 Bs[128][40];

    const int tid = threadIdx.x;
    const int lane = tid & 63, wv = tid >> 6;
    const int wr = wv >> 1, wc = wv & 1;
    const int quad = lane >> 4, l16 = lane & 15;

    f32x4 acc[4][4];
    #pragma unroll
    for (int i = 0; i < 4; i++)
        #pragma unroll
        for (int j = 0; j < 4; j++)
            acc[i][j] = (f32x4){0.f, 0.f, 0.f, 0.f};

    for (int k0 = 0; k0 < K; k0 += 32) {
        // stage A
        if constexpr (A_BF16) {
            const bf16* A = (const bf16*)Av;
            #pragma unroll
            for (int i = 0; i < 2; i++) {
                int row = (tid >> 2) + i * 64, seg = tid & 3;
                bf16x8 v = *(const bf16x8*)&A[(size_t)(bm + row) * K + k0 + seg * 8];
                *(bf16x8*)&As[row][seg * 8] = v;
            }
        } else {
            const float* A = (const float*)Av;
            #pragma unroll
            for (int i = 0; i < 4; i++) {
                int row = (tid >> 3) + i * 32, f4 = tid & 7;
                float4 f = *(const float4*)&A[(size_t)(bm + row) * K + k0 + f4 * 4];
                bf16x4 h;
                h[0] = (bf16)f.x; h[1] = (bf16)f.y; h[2] = (bf16)f.z; h[3] = (bf16)f.w;
                *(bf16x4*)&As[row][f4 * 4] = h;
            }
        }
        // stage B (WT rows are k-contiguous)
        #pragma unroll
        for (int i = 0; i < 2; i++) {
            int row = (tid >> 2) + i * 64, seg = tid & 3;
            bf16x8 v = *(const bf16x8*)&WT[(size_t)(bn + row) * K + k0 + seg * 8];
            *(bf16x8*)&Bs[row][seg * 8] = v;
        }
        __syncthreads();

        bf16x8 af[4], bfr[4];
        #pragma unroll
        for (int mi = 0; mi < 4; mi++)
            af[mi] = *(const bf16x8*)&As[wr * 64 + mi * 16 + l16][quad * 8];
        #pragma unroll
        for (int ni = 0; ni < 4; ni++)
            bfr[ni] = *(const bf16x8*)&Bs[wc * 64 + ni * 16 + l16][quad * 8];
        #pragma unroll
        for (int mi = 0; mi < 4; mi++)
            #pragma unroll
            for (int ni = 0; ni < 4; ni++)
                acc[mi][ni] = __builtin_amdgcn_mfma_f32_16x16x32_bf16(
                    af[mi], bfr[ni], acc[mi][ni], 0, 0, 0);
        __syncthreads();
    }

    // epilogue
    #pragma unroll
    for (int mi = 0; mi < 4; mi++) {
        #pragma unroll
        for (int ni = 0; ni < 4; ni++) {
            const int col = bn + wc * 64 + ni * 16 + l16;
            const int row0 = bm + wr * 64 + mi * 16 + quad * 4;
            const float bc = bias[col];
            #pragma unroll
            for (int r = 0; r < 4; r++) {
                float v = acc[mi][ni][r] + bc;
                if constexpr (OUT_BF16)
                    ((bf16*)Cv)[(size_t)(row0 + r) * N + col] = (bf16)v;
                else
                    ((float*)Cv)[(size_t)(row0 + r) * N + col] = v;
            }
        }
    }
}

// ---------------- Deformable sampling: one wave per query.
// vproj: bf16 [BS,V,256]; offaw: fp32 [BS*NQ,384] (off 0..255, attn logits 256..383)
// sampled: bf16 [BS*NQ,256]
__global__ __launch_bounds__(64) void deform_sample(
    const bf16* __restrict__ vproj, const float* __restrict__ offaw,
    const float* __restrict__ refp, bf16* __restrict__ sampled)
{
    const int q = blockIdx.x;
    const int b = blockIdx.y;
    const int bq = b * NQ + q;
    const int t = threadIdx.x;

    __shared__ float s_off[256];
    __shared__ float s_aw[128];
    __shared__ __align__(16) float s_w[128][4];   // indexed [lp*8+h]
    __shared__ __align__(16) int   s_idx[128][4];

    const float* row = offaw + (size_t)bq * 384;
    #pragma unroll
    for (int i = 0; i < 4; i++) s_off[t + i * 64] = row[t + i * 64];
    #pragma unroll
    for (int i = 0; i < 2; i++) s_aw[t + i * 64] = row[256 + t + i * 64];
    __syncthreads();

    // softmax per head (8 groups of 16)
    if (t < 8) {
        float m = -1e30f;
        #pragma unroll
        for (int i = 0; i < 16; i++) m = fmaxf(m, s_aw[t * 16 + i]);
        float ssum = 0.f;
        #pragma unroll
        for (int i = 0; i < 16; i++) {
            float e = __expf(s_aw[t * 16 + i] - m);
            s_aw[t * 16 + i] = e;
            ssum += e;
        }
        float r = 1.0f / ssum;
        #pragma unroll
        for (int i = 0; i < 16; i++) s_aw[t * 16 + i] *= r;
    }
    __syncthreads();

    // precompute 128 samples: row indices + aw-fused bilinear weights
    #pragma unroll
    for (int sI = 0; sI < 2; sI++) {
        int s = t + sI * 64;
        int h = s >> 4, lp = s & 15, l = lp >> 2, p = lp & 3;
        int Wl = 128 >> l, Hl = 128 >> l;
        int st = (l == 0) ? 0 : (l == 1) ? 16384 : (l == 2) ? 20480 : 21504;
        float rx = refp[((size_t)bq * 4 + l) * 2 + 0];
        float ry = refp[((size_t)bq * 4 + l) * 2 + 1];
        float ox = s_off[((h * NL + l) * NP + p) * 2 + 0];
        float oy = s_off[((h * NL + l) * NP + p) * 2 + 1];
        float fW = (float)Wl, fH = (float)Hl;
        float x = (rx + ox / fW) * fW - 0.5f;
        float y = (ry + oy / fH) * fH - 0.5f;
        float xf = floorf(x), yf = floorf(y);
        int x0 = (int)xf, y0 = (int)yf;
        float wx1 = x - xf, wx0 = 1.f - wx1;
        float wy1 = y - yf, wy0 = 1.f - wy1;
        float aw = s_aw[h * 16 + lp];
        bool vx0 = (x0 >= 0) && (x0 < Wl);
        bool vx1 = (x0 + 1 >= 0) && (x0 + 1 < Wl);
        bool vy0 = (y0 >= 0) && (y0 < Hl);
        bool vy1 = (y0 + 1 >= 0) && (y0 + 1 < Hl);
        int cx0 = min(max(x0, 0), Wl - 1), cx1 = min(max(x0 + 1, 0), Wl - 1);
        int cy0 = min(max(y0, 0), Hl - 1), cy1 = min(max(y0 + 1, 0), Hl - 1);
        int d = lp * 8 + h;  // bank-spread layout
        s_idx[d][0] = st + cy0 * Wl + cx0;  s_w[d][0] = (vy0 && vx0) ? wy0 * wx0 * aw : 0.f;
        s_idx[d][1] = st + cy0 * Wl + cx1;  s_w[d][1] = (vy0 && vx1) ? wy0 * wx1 * aw : 0.f;
        s_idx[d][2] = st + cy1 * Wl + cx0;  s_w[d][2] = (vy1 && vx0) ? wy1 * wx0 * aw : 0.f;
        s_idx[d][3] = st + cy1 * Wl + cx1;  s_w[d][3] = (vy1 && vx1) ? wy1 * wx1 * aw : 0.f;
    }
    __syncthreads();

    // gather: thread t owns head h = t>>3, channels choff = t*4 .. t*4+3
    const int h = t >> 3;
    const int choff = t * 4;
    const bf16* vbc = vproj + (size_t)b * V_LEN * EMBED + choff;
    float a0 = 0.f, a1 = 0.f, a2 = 0.f, a3 = 0.f;
    #pragma unroll 4
    for (int lp = 0; lp < 16; lp++) {
        const int d = lp * 8 + h;
        const float4 w4 = *(const float4*)&s_w[d][0];
        const int4  i4 = *(const int4*)&s_idx[d][0];
        bf16x4 v0 = *(const bf16x4*)(vbc + (i4.x << 8));
        bf16x4 v1 = *(const bf16x4*)(vbc + (i4.y << 8));
        bf16x4 v2 = *(const bf16x4*)(vbc + (i4.z << 8));
        bf16x4 v3 = *(const bf16x4*)(vbc + (i4.w << 8));
        a0 += w4.x * (float)v0[0] + w4.y * (float)v1[0] + w4.z * (float)v2[0] + w4.w * (float)v3[0];
        a1 += w4.x * (float)v0[1] + w4.y * (float)v1[1] + w4.z * (float)v2[1] + w4.w * (float)v3[1];
        a2 += w4.x * (float)v0[2] + w4.y * (float)v1[2] + w4.z * (float)v2[2] + w4.w * (float)v3[2];
        a3 += w4.x * (float)v0[3] + w4.y * (float)v1[3] + w4.z * (float)v2[3] + w4.w * (float)v3[3];
    }

    bf16x4 o;
    o[0] = (bf16)a0; o[1] = (bf16)a1; o[2] = (bf16)a2; o[3] = (bf16)a3;
    *(bf16x4*)&sampled[(size_t)bq * 256 + choff] = o;
}

extern "C" void kernel_launch(void* const* d_in, const int* in_sizes, int n_in,
                              void* d_out, int out_size, void* d_ws, size_t ws_size,
                              hipStream_t stream)
{
    const float* query  = (const float*)d_in[0];
    const float* refp   = (const float*)d_in[1];
    const float* value  = (const float*)d_in[2];
    const float* W_off  = (const float*)d_in[3];
    const float* b_off  = (const float*)d_in[4];
    const float* W_attn = (const float*)d_in[5];
    const float* b_attn = (const float*)d_in[6];
    const float* W_v    = (const float*)d_in[7];
    const float* b_v    = (const float*)d_in[8];
    const float* W_out  = (const float*)d_in[9];
    const float* b_out  = (const float*)d_in[10];
    float* out = (float*)d_out;

    const int M = BS * NQ;  // 43520

    char* ws = (char*)d_ws;
    bf16*  WTv   = (bf16*)ws;                      ws += 256 * 256 * 2;
    bf16*  WToa  = (bf16*)ws;                      ws += 384 * 256 * 2;
    bf16*  WTu   = (bf16*)ws;                      ws += 256 * 256 * 2;
    float* bcat  = (float*)ws;                     ws += 384 * 4;
    bf16*  vproj = (bf16*)ws;                      ws += (size_t)M * 256 * 2;
    float* offaw = (float*)ws;                     ws += (size_t)M * 384 * 4;
    bf16*  samp  = (bf16*)ws;                      ws += (size_t)M * 256 * 2;

    cast_wt<<<256, 256, 0, stream>>>(W_v,   WTv, 256);
    cast_wt<<<256, 256, 0, stream>>>(W_off, WToa, 256);
    cast_wt<<<128, 256, 0, stream>>>(W_attn, WToa + 256 * 256, 128);
    cast_wt<<<256, 256, 0, stream>>>(W_out, WTu, 256);
    concat_bias<<<1, 384, 0, stream>>>(b_off, b_attn, bcat);

    // vproj = bf16(value @ W_v + b_v)
    gemm_mfma<false, true><<<(M / 128) * 2, 256, 0, stream>>>(value, WTv, b_v, vproj, 256, 256, 2);
    // offaw = query @ [W_off | W_attn] + [b_off | b_attn]   (fp32 out)
    gemm_mfma<false, false><<<(M / 128) * 3, 256, 0, stream>>>(query, WToa, bcat, offaw, 384, 256, 3);
    // softmax + deformable sampling -> bf16
    deform_sample<<<dim3(NQ, BS), dim3(64), 0, stream>>>(vproj, offaw, refp, samp);
    // out = sampled @ W_out + b_out  (fp32 out)
    gemm_mfma<true, false><<<(M / 128) * 2, 256, 0, stream>>>(samp, WTu, b_out, out, 256, 256, 2);
}